// Round 5
// baseline (2310.105 us; speedup 1.0000x reference)
//
#include <hip/hip_runtime.h>
#include <stdint.h>

#define VOCAB 32000
#define EMB   1024
#define HID   1024
#define BATCH 16
#define SEQ   256
#define MROWS (SEQ*BATCH)   // 4096

typedef unsigned short u16;
typedef uint32_t u32;
typedef __bf16 bf16x8 __attribute__((ext_vector_type(8)));
typedef float  f32x4  __attribute__((ext_vector_type(4)));
typedef u32    u32x4  __attribute__((ext_vector_type(4)));

static __device__ __forceinline__ u16 f2bf(float f) {
  union { float f; uint32_t u; } v; v.f = f;
  return (u16)((v.u + 0x7FFFu + ((v.u >> 16) & 1u)) >> 16);  // RNE
}

static __device__ __forceinline__ f32x4 MFMA(bf16x8 a, bf16x8 b, f32x4 c) {
  return __builtin_amdgcn_mfma_f32_16x16x32_bf16(a, b, c, 0, 0, 0);
}

// ---- coherent (XCD-bypass) memory helpers: batched loads, one wait ----
static __device__ __forceinline__ void load8_coh(const void* p, bf16x8* r) {
  asm volatile(
    "global_load_dwordx4 %0, %8, off sc0 sc1\n\t"
    "global_load_dwordx4 %1, %8, off offset:64 sc0 sc1\n\t"
    "global_load_dwordx4 %2, %8, off offset:128 sc0 sc1\n\t"
    "global_load_dwordx4 %3, %8, off offset:192 sc0 sc1\n\t"
    "global_load_dwordx4 %4, %8, off offset:256 sc0 sc1\n\t"
    "global_load_dwordx4 %5, %8, off offset:320 sc0 sc1\n\t"
    "global_load_dwordx4 %6, %8, off offset:384 sc0 sc1\n\t"
    "global_load_dwordx4 %7, %8, off offset:448 sc0 sc1\n\t"
    "s_waitcnt vmcnt(0)"
    : "=&v"(r[0]), "=&v"(r[1]), "=&v"(r[2]), "=&v"(r[3]),
      "=&v"(r[4]), "=&v"(r[5]), "=&v"(r[6]), "=&v"(r[7])
    : "v"(p) : "memory");
}

static __device__ __forceinline__ void load16_coh(const void* p, bf16x8* r) {
  asm volatile(
    "global_load_dwordx4 %0, %16, off sc0 sc1\n\t"
    "global_load_dwordx4 %1, %16, off offset:64 sc0 sc1\n\t"
    "global_load_dwordx4 %2, %16, off offset:128 sc0 sc1\n\t"
    "global_load_dwordx4 %3, %16, off offset:192 sc0 sc1\n\t"
    "global_load_dwordx4 %4, %16, off offset:256 sc0 sc1\n\t"
    "global_load_dwordx4 %5, %16, off offset:320 sc0 sc1\n\t"
    "global_load_dwordx4 %6, %16, off offset:384 sc0 sc1\n\t"
    "global_load_dwordx4 %7, %16, off offset:448 sc0 sc1\n\t"
    "global_load_dwordx4 %8, %16, off offset:512 sc0 sc1\n\t"
    "global_load_dwordx4 %9, %16, off offset:576 sc0 sc1\n\t"
    "global_load_dwordx4 %10, %16, off offset:640 sc0 sc1\n\t"
    "global_load_dwordx4 %11, %16, off offset:704 sc0 sc1\n\t"
    "global_load_dwordx4 %12, %16, off offset:768 sc0 sc1\n\t"
    "global_load_dwordx4 %13, %16, off offset:832 sc0 sc1\n\t"
    "global_load_dwordx4 %14, %16, off offset:896 sc0 sc1\n\t"
    "global_load_dwordx4 %15, %16, off offset:960 sc0 sc1\n\t"
    "s_waitcnt vmcnt(0)"
    : "=&v"(r[0]), "=&v"(r[1]), "=&v"(r[2]), "=&v"(r[3]),
      "=&v"(r[4]), "=&v"(r[5]), "=&v"(r[6]), "=&v"(r[7]),
      "=&v"(r[8]), "=&v"(r[9]), "=&v"(r[10]), "=&v"(r[11]),
      "=&v"(r[12]), "=&v"(r[13]), "=&v"(r[14]), "=&v"(r[15])
    : "v"(p) : "memory");
}

static __device__ __forceinline__ void store_u16_coh(u16* p, u16 v) {
  asm volatile("global_store_short %0, %1, off sc0 sc1"
               :: "v"(p), "v"((u32)v) : "memory");
}
static __device__ __forceinline__ void wait_vm0() {
  asm volatile("s_waitcnt vmcnt(0)" ::: "memory");
}

// poll a 64B flag line (32 u16 slots): 1 if ALL slots equal the splatted pattern
static __device__ __forceinline__ int flags_ready(const void* p, u32 pat) {
  u32x4 a, b, c, d;
  asm volatile(
    "global_load_dwordx4 %0, %4, off sc0 sc1\n\t"
    "global_load_dwordx4 %1, %4, off offset:16 sc0 sc1\n\t"
    "global_load_dwordx4 %2, %4, off offset:32 sc0 sc1\n\t"
    "global_load_dwordx4 %3, %4, off offset:48 sc0 sc1\n\t"
    "s_waitcnt vmcnt(0)"
    : "=&v"(a), "=&v"(b), "=&v"(c), "=&v"(d)
    : "v"(p) : "memory");
  u32 m = (a[0]^pat)|(a[1]^pat)|(a[2]^pat)|(a[3]^pat)
        | (b[0]^pat)|(b[1]^pat)|(b[2]^pat)|(b[3]^pat)
        | (c[0]^pat)|(c[1]^pat)|(c[2]^pat)|(c[3]^pat)
        | (d[0]^pat)|(d[1]^pat)|(d[2]^pat)|(d[3]^pat);
  return m == 0u;
}

// ---------------- converts ----------------

// hidden -> bf16 init vectors; also zero the flag lines (16384 u32 = 64KB)
__global__ void cvt_hidden(const float* __restrict__ hidden,
                           u16* __restrict__ h0i, u16* __restrict__ h1i,
                           unsigned* __restrict__ flags) {
  int i = blockIdx.x * 256 + threadIdx.x;
  if (i < 16384) flags[i] = 0u;
  if (i < BATCH * HID)            h0i[i] = f2bf(hidden[i]);
  else if (i < 2 * BATCH * HID)   h1i[i - BATCH * HID] = f2bf(hidden[i]);
}

// (K=1024 x N=1024) f32 row-major  ->  (N,K) bf16
__global__ void transpose_cvt(const float* __restrict__ in, u16* __restrict__ out) {
  __shared__ float tile[32][33];
  int bx = blockIdx.x * 32;   // N
  int by = blockIdx.y * 32;   // K
  int tx = threadIdx.x, ty = threadIdx.y;   // (32,8)
  #pragma unroll
  for (int i = 0; i < 32; i += 8)
    tile[ty + i][tx] = in[(size_t)(by + ty + i) * HID + bx + tx];
  __syncthreads();
  #pragma unroll
  for (int i = 0; i < 32; i += 8)
    out[(size_t)(bx + ty + i) * HID + by + tx] = f2bf(tile[tx][ty + i]);
}

__global__ void cvt_emb(const float4* __restrict__ in, ushort4* __restrict__ out, int n4) {
  int stride = gridDim.x * blockDim.x;
  for (int i = blockIdx.x * blockDim.x + threadIdx.x; i < n4; i += stride) {
    float4 v = in[i];
    ushort4 o; o.x = f2bf(v.x); o.y = f2bf(v.y); o.z = f2bf(v.z); o.w = f2bf(v.w);
    out[i] = o;
  }
}

__global__ void gather_emb(const int* __restrict__ x, const float* __restrict__ embW,
                           u16* __restrict__ E) {
  int r = blockIdx.x;               // 0..4095
  int b = r & 15, t = r >> 4;
  int idx = x[b * SEQ + t];
  const float4* src = (const float4*)(embW + (size_t)idx * EMB);
  ushort4* dst = (ushort4*)(E + (size_t)r * EMB);
  float4 v = src[threadIdx.x];
  ushort4 o; o.x = f2bf(v.x); o.y = f2bf(v.y); o.z = f2bf(v.z); o.w = f2bf(v.w);
  dst[threadIdx.x] = o;
}

// ---------------- 128x128 MFMA GEMM, C = A(MxK) @ B(NxK)^T + bias ----------------
template <int OUTMODE>
__global__ __launch_bounds__(256) void gemm_bt(
    const u16* __restrict__ A, const u16* __restrict__ B,
    const float* __restrict__ bias, float* __restrict__ C,
    int M, int N, int K)
{
  __shared__ __align__(16) char lds[32768];
  char* As = lds;
  char* Bs = lds + 16384;
  const int tid  = threadIdx.x;
  const int lane = tid & 63;
  const int wave = tid >> 6;
  const int wr = wave >> 1, wc = wave & 1;
  const int bm = blockIdx.y * 128;
  const int bn = blockIdx.x * 128;
  const int srow = tid >> 3;
  const int swc  = (tid & 7) ^ (srow & 7);

  f32x4 acc[4][4];
  #pragma unroll
  for (int i = 0; i < 4; ++i)
    #pragma unroll
    for (int j = 0; j < 4; ++j) acc[i][j] = (f32x4){0.f, 0.f, 0.f, 0.f};

  const u16* Ab = A + (size_t)(bm + srow) * K + swc * 8;
  const u16* Bb = B + (size_t)(bn + srow) * K + swc * 8;
  const size_t rstep = (size_t)32 * K;

  for (int k0 = 0; k0 < K; k0 += 64) {
    #pragma unroll
    for (int i = 0; i < 4; ++i) {
      __builtin_amdgcn_global_load_lds(
          (const __attribute__((address_space(1))) void*)(Ab + i * rstep + k0),
          (__attribute__((address_space(3))) void*)(As + i * 4096 + wave * 1024),
          16, 0, 0);
      __builtin_amdgcn_global_load_lds(
          (const __attribute__((address_space(1))) void*)(Bb + i * rstep + k0),
          (__attribute__((address_space(3))) void*)(Bs + i * 4096 + wave * 1024),
          16, 0, 0);
    }
    __syncthreads();
    #pragma unroll
    for (int ks = 0; ks < 2; ++ks) {
      bf16x8 af[4], bq[4];
      #pragma unroll
      for (int mi = 0; mi < 4; ++mi) {
        int row = wr * 64 + mi * 16 + (lane & 15);
        int c = (ks * 4 + (lane >> 4)) ^ (row & 7);
        af[mi] = *(const bf16x8*)(As + row * 128 + c * 16);
      }
      #pragma unroll
      for (int ni = 0; ni < 4; ++ni) {
        int row = wc * 64 + ni * 16 + (lane & 15);
        int c = (ks * 4 + (lane >> 4)) ^ (row & 7);
        bq[ni] = *(const bf16x8*)(Bs + row * 128 + c * 16);
      }
      #pragma unroll
      for (int mi = 0; mi < 4; ++mi)
        #pragma unroll
        for (int ni = 0; ni < 4; ++ni)
          acc[mi][ni] = MFMA(af[mi], bq[ni], acc[mi][ni]);
    }
    __syncthreads();
  }

  #pragma unroll
  for (int mi = 0; mi < 4; ++mi) {
    #pragma unroll
    for (int ni = 0; ni < 4; ++ni) {
      const int col = bn + wc * 64 + ni * 16 + (lane & 15);
      const float bv = bias[col];
      #pragma unroll
      for (int j = 0; j < 4; ++j) {
        const int row = bm + wr * 64 + mi * 16 + ((lane >> 4) << 2) + j;
        const float v = acc[mi][ni][j] + bv;
        size_t off;
        if (OUTMODE == 0)
          off = (size_t)row * N + col;
        else
          off = (size_t)(row & 15) * ((size_t)SEQ * VOCAB) + (size_t)(row >> 4) * VOCAB + col;
        C[off] = v;
      }
    }
  }
}

// ---------------- fused 2-layer recurrence, write-slot flags (no atomics) ----------------
// 64 blocks x 512 threads. Blocks 0..31: layer 0; 32..63: layer 1.
// flags0[s]: 64B line, u16 slot per L0 block, value s+1 when h0(s) published.
// flags1[t]: same for layer 1. Lines are 128B-strided. No RMW atomics, no fences;
// h exchanged via sc0sc1 write-through stores / coherent batched loads.
#define NB0L 32
#define NBLK 64
#define COMB_OFF 131072
#define LDS_TOTAL (COMB_OFF + 8192)
#define FLINE 128

__global__ __launch_bounds__(512) void recurrence(
    const u16* __restrict__ Wh0T, const u16* __restrict__ Wx1T, const u16* __restrict__ Wh1T,
    const float* __restrict__ X0,       // 4096x1024 f32, includes b0
    const float* __restrict__ b1,
    const u16* __restrict__ h0init, const u16* __restrict__ h1init,
    u16* H0, u16* H1,                   // 4096x1024 bf16, coherent-exchanged
    float* __restrict__ hidOut,         // (2,16,1024) f32 at d_out tail
    char* flags)                        // 64KB: flags0 at 0, flags1 at +32KB
{
  __shared__ __align__(16) char lds[LDS_TOTAL];
  const int tid  = threadIdx.x;
  const int lane = tid & 63;
  const int w    = tid >> 6;           // 0..7
  const int l15  = lane & 15;
  const int lk   = lane >> 4;          // 0..3
  const int blk  = blockIdx.x;
  const bool is0 = (blk < NB0L);
  float* comb = (float*)(lds + COMB_OFF);
  char* f0 = flags;
  char* f1 = flags + 32768;

  // ---- stage weight slice(s) into LDS: frag f = k/8 (16B), offset = f*512 + brow*16 ----
  if (is0) {
    const u16* src = Wh0T + (size_t)(blk * 32) * HID;
    for (int it = 0; it < 8; ++it) {
      int g = it * 512 + tid;                 // 0..4095
      int brow = g & 31, f = g >> 5;          // f 0..127
      *(bf16x8*)(lds + f * 512 + brow * 16) =
          *(const bf16x8*)(src + (size_t)brow * HID + f * 8);
    }
  } else {
    const u16* s0 = Wx1T + (size_t)((blk - NB0L) * 32) * HID;
    const u16* s1 = Wh1T + (size_t)((blk - NB0L) * 32) * HID;
    for (int it = 0; it < 8; ++it) {
      int g = it * 512 + tid;
      int brow = g & 31, f = g >> 5;
      int o = f * 512 + brow * 16;
      *(bf16x8*)(lds + o)         = *(const bf16x8*)(s0 + (size_t)brow * HID + f * 8);
      *(bf16x8*)(lds + 65536 + o) = *(const bf16x8*)(s1 + (size_t)brow * HID + f * 8);
    }
  }
  __syncthreads();

  if (is0) {
    const int q  = w >> 1;                    // K-quarter 0..3
    const int ct = w & 1;
    const int brow = ct * 16 + l15;
    const int col  = blk * 32 + brow;
    float xv[4];
    if (w < 2) {
      #pragma unroll
      for (int j = 0; j < 4; ++j)
        xv[j] = X0[(size_t)(lk * 4 + j) * HID + col];     // s = 0
    }
    for (int s = 0; s < SEQ; ++s) {
      // entry invariant: flags0[s-1] fully set (h0(s-1) visible)
      const u16* hsrc = (s == 0) ? h0init : (H0 + (size_t)(s - 1) * BATCH * HID);
      const char* ap = (const char*)hsrc + l15 * 2048 + q * 512 + lk * 16;
      bf16x8 a[8];
      load8_coh(ap, a);
      f32x4 ae = {0,0,0,0}, ao = {0,0,0,0};
      #pragma unroll
      for (int m = 0; m < 8; m += 2) {
        ae = MFMA(a[m],     *(const bf16x8*)(lds + (q*32 + m*4 + lk)*512 + brow*16), ae);
        ao = MFMA(a[m + 1], *(const bf16x8*)(lds + (q*32 + (m+1)*4 + lk)*512 + brow*16), ao);
      }
      f32x4 acc = ae + ao;
      if (w >= 2) *(f32x4*)(comb + ((size_t)w * 64 + lane) * 4) = acc;
      __syncthreads();
      if (w < 2) {
        f32x4 p2 = *(const f32x4*)(comb + ((size_t)(w + 2) * 64 + lane) * 4);
        f32x4 p4 = *(const f32x4*)(comb + ((size_t)(w + 4) * 64 + lane) * 4);
        f32x4 p6 = *(const f32x4*)(comb + ((size_t)(w + 6) * 64 + lane) * 4);
        acc = (acc + p2) + (p4 + p6);
        #pragma unroll
        for (int j = 0; j < 4; ++j) {
          const int b = lk * 4 + j;
          float v = tanhf(acc[j] + xv[j]);
          store_u16_coh(H0 + (size_t)(s * BATCH + b) * HID + col, f2bf(v));
          if (s == SEQ - 1) hidOut[(size_t)b * HID + col] = v;
        }
        wait_vm0();
        if (s + 1 < SEQ) {                    // prefetch X0 for next step
          #pragma unroll
          for (int j = 0; j < 4; ++j)
            xv[j] = X0[(size_t)((s + 1) * BATCH + lk * 4 + j) * HID + col];
        }
      }
      __syncthreads();                        // all h0(s) stores drained block-wide
      if (tid == 0) {
        store_u16_coh((u16*)(f0 + (size_t)s * FLINE) + blk, (u16)(s + 1));
        if (s + 1 < SEQ) {
          const u32 pat = (u32)(s + 1) * 0x10001u;
          while (!flags_ready(f0 + (size_t)s * FLINE, pat)) {}
        }
      }
      if (s + 1 < SEQ) __syncthreads();
    }
  } else {
    const int kh  = w >> 2;                   // K-half
    const int mat = (w >> 1) & 1;             // 0: Wx1 (vs h0(t)), 1: Wh1 (vs h1(t-1))
    const int ct  = w & 1;
    const int brow = ct * 16 + l15;
    const int col  = (blk - NB0L) * 32 + brow;
    const float bv = b1[col];
    const char* wb = lds + mat * 65536;
    if (tid == 0) { while (!flags_ready(f0, 0x10001u)) {} }   // wait h0(0)
    __syncthreads();
    for (int t = 0; t < SEQ; ++t) {
      // entry invariant: flags0[t] set and (t==0 || flags1[t-1] set)
      const u16* hsrc = mat ? ((t == 0) ? h1init : (H1 + (size_t)(t - 1) * BATCH * HID))
                            : (H0 + (size_t)t * BATCH * HID);
      const char* ap = (const char*)hsrc + l15 * 2048 + kh * 1024 + lk * 16;
      bf16x8 a[16];
      load16_coh(ap, a);
      f32x4 ae = {0,0,0,0}, ao = {0,0,0,0};
      #pragma unroll
      for (int m = 0; m < 16; m += 2) {
        ae = MFMA(a[m],     *(const bf16x8*)(wb + (kh*64 + m*4 + lk)*512 + brow*16), ae);
        ao = MFMA(a[m + 1], *(const bf16x8*)(wb + (kh*64 + (m+1)*4 + lk)*512 + brow*16), ao);
      }
      f32x4 acc = ae + ao;
      if (w >= 2) *(f32x4*)(comb + ((size_t)w * 64 + lane) * 4) = acc;
      __syncthreads();
      if (w < 2) {
        f32x4 p2 = *(const f32x4*)(comb + ((size_t)(w + 2) * 64 + lane) * 4);
        f32x4 p4 = *(const f32x4*)(comb + ((size_t)(w + 4) * 64 + lane) * 4);
        f32x4 p6 = *(const f32x4*)(comb + ((size_t)(w + 6) * 64 + lane) * 4);
        acc = (acc + p2) + (p4 + p6);
        #pragma unroll
        for (int j = 0; j < 4; ++j) {
          const int b = lk * 4 + j;
          float v = tanhf(acc[j] + bv);
          store_u16_coh(H1 + (size_t)(t * BATCH + b) * HID + col, f2bf(v));
          if (t == SEQ - 1) hidOut[(size_t)(BATCH * HID) + (size_t)b * HID + col] = v;
        }
        wait_vm0();
      }
      __syncthreads();                        // all h1(t) stores drained block-wide
      if (t + 1 < SEQ) {
        if (tid == 0) {
          store_u16_coh((u16*)(f1 + (size_t)t * FLINE) + (blk - NB0L), (u16)(t + 1));
          const u32 pat = (u32)(t + 2) * 0x10001u;          // flags0[t+1] ready?
          while (!flags_ready(f0 + (size_t)(t + 1) * FLINE, pat)) {}
        }
        if (tid == 64) {
          const u32 pat = (u32)(t + 1) * 0x10001u;          // flags1[t] ready?
          while (!flags_ready(f1 + (size_t)t * FLINE, pat)) {}
        }
        __syncthreads();
      }
    }
  }
}

// ---------------- launch ----------------
extern "C" void kernel_launch(void* const* d_in, const int* in_sizes, int n_in,
                              void* d_out, int out_size, void* d_ws, size_t ws_size,
                              hipStream_t stream) {
  const int*   x      = (const int*)  d_in[0];
  const float* hidden = (const float*)d_in[1];
  const float* embW   = (const float*)d_in[2];
  const float* Wx0    = (const float*)d_in[3];
  const float* Wh0    = (const float*)d_in[4];
  const float* b0     = (const float*)d_in[5];
  const float* Wx1    = (const float*)d_in[6];
  const float* Wh1    = (const float*)d_in[7];
  const float* b1     = (const float*)d_in[8];
  const float* outb   = (const float*)d_in[9];
  float* out = (float*)d_out;

  char* ws = (char*)d_ws;
  size_t off = 0;
  auto alloc = [&](size_t bytes) {
    char* p = ws + off; off += (bytes + 255) & ~(size_t)255; return p;
  };
  u16*   embB = (u16*)  alloc((size_t)VOCAB * EMB * 2);
  u16*   Wx0T = (u16*)  alloc((size_t)EMB * HID * 2);
  u16*   Wh0T = (u16*)  alloc((size_t)HID * HID * 2);
  u16*   Wx1T = (u16*)  alloc((size_t)HID * HID * 2);
  u16*   Wh1T = (u16*)  alloc((size_t)HID * HID * 2);
  u16*   E    = (u16*)  alloc((size_t)MROWS * EMB * 2);
  float* X0f  = (float*)alloc((size_t)MROWS * HID * 4);
  u16*   H0   = (u16*)  alloc((size_t)MROWS * HID * 2);
  u16*   H1   = (u16*)  alloc((size_t)MROWS * HID * 2);
  u16*   h0i  = (u16*)  alloc((size_t)BATCH * HID * 2);
  u16*   h1i  = (u16*)  alloc((size_t)BATCH * HID * 2);
  char*  flags = (char*)alloc(65536);   // flags0[256] + flags1[256], 128B lines
  if (off > ws_size) return;

  cvt_hidden<<<dim3(128), dim3(256), 0, stream>>>(hidden, h0i, h1i, (unsigned*)flags);

  dim3 tb(32, 8), tg(32, 32);
  transpose_cvt<<<tg, tb, 0, stream>>>(Wx0, Wx0T);
  transpose_cvt<<<tg, tb, 0, stream>>>(Wh0, Wh0T);
  transpose_cvt<<<tg, tb, 0, stream>>>(Wx1, Wx1T);
  transpose_cvt<<<tg, tb, 0, stream>>>(Wh1, Wh1T);

  cvt_emb<<<dim3(2048), dim3(256), 0, stream>>>(
      (const float4*)embW, (ushort4*)embB, (int)((size_t)VOCAB * EMB / 4));
  gather_emb<<<dim3(MROWS), dim3(256), 0, stream>>>(x, embW, E);

  // X0 = E @ Wx0^T + b0   (4096x1024)
  gemm_bt<0><<<dim3(HID / 128, MROWS / 128), dim3(256), 0, stream>>>(
      E, Wx0T, b0, X0f, MROWS, HID, EMB);

  // fused recurrence: writes H0, H1 and final hidden into d_out tail
  recurrence<<<dim3(NBLK), dim3(512), 0, stream>>>(
      Wh0T, Wx1T, Wh1T, X0f, b1, h0i, h1i, H0, H1,
      out + (size_t)BATCH * SEQ * VOCAB, flags);

  // logits = H1 @ emb^T + out_b   (4096x32000, remapped to (B,T,V))
  gemm_bt<1><<<dim3(VOCAB / 128, MROWS / 128), dim3(256), 0, stream>>>(
      H1, embB, outb, out, MROWS, VOCAB, EMB);
}